// Round 1
// 185.465 us; speedup vs baseline: 1.1230x; 1.1230x over previous
//
#include <hip/hip_runtime.h>

// ---------------------------------------------------------------------------
// EMLLocalMessageBlock on MI355X — round 4.
//   x@W1 = center@(W1a+W1c) + nbhd@(W1b-W1c) + rel@W1d + b1
//   update = [Sum_n g_n (A_n @ VoW)]/mass + (vb@oW)*(sg/mass) + ob
// K-permutation (torch-reshape scramble): slot k'=16r+t <-> c2 = r+9t;
// per (n2,r): shift n=(2*n2+r)%9, channels c=c0+t, c0=(n2*128+r)/9.
// All LDS tiles use row stride AW=152 elems (304 B = 76 dw = 12 mod 32:
// ds_read_b128 lanes 0..7 tile all 8 bank-groups -> conflict-free).
// Round-4 deltas: DPP reductions (no ds_bpermute on the DS pipe),
// register-prefetched gather (loads issued before edge GEMM, LDS write
// after sync A), per-iter barrier count 3 -> 2.
// ---------------------------------------------------------------------------

#define USHORT unsigned short
#define AW 152

typedef __attribute__((ext_vector_type(8)))  __bf16 v8bf;
typedef __attribute__((ext_vector_type(8)))  USHORT v8u;
typedef __attribute__((ext_vector_type(16))) float  v16f;

__device__ __forceinline__ USHORT f2bf(float f) {
    unsigned v; __builtin_memcpy(&v, &f, 4);
    v += 0x7FFFu + ((v >> 16) & 1u);
    return (USHORT)(v >> 16);
}

// ---- DPP helpers: pure-VALU cross-lane sums (DS pipe stays free) ----------
template <int C>
__device__ __forceinline__ float dpps(float x) {
    return __int_as_float(
        __builtin_amdgcn_update_dpp(0, __float_as_int(x), C, 0xf, 0xf, true));
}
// sum of lanes 0..31 lands in lane 31; sum of lanes 32..63 lands in lane 63
__device__ __forceinline__ float red32half(float x) {
    x += dpps<0x111>(x);   // row_shr:1
    x += dpps<0x112>(x);   // row_shr:2
    x += dpps<0x114>(x);   // row_shr:4
    x += dpps<0x118>(x);   // row_shr:8
    x += dpps<0x142>(x);   // row_bcast:15
    return x;
}
// full 64-lane sum lands in lane 63
__device__ __forceinline__ float red64(float x) {
    x = red32half(x);
    x += dpps<0x143>(x);   // row_bcast:31
    return x;
}
__device__ __forceinline__ float bcast63(float x) {
    return __int_as_float(__builtin_amdgcn_readlane(__float_as_int(x), 63));
}

// ---------------------------------------------------------------------------
// k_setup: blocks [0,354) = weight prep, blocks [354,8546) = LN1.
// (byte-identical to round 3 — keeps the dur_us-minus-k_edge subtraction a
//  clean probe of the unprofiled ~99 us)
// ---------------------------------------------------------------------------
__global__ __launch_bounds__(256) void k_setup(
    const float* __restrict__ tok, const float* __restrict__ ln1g,
    const float* __restrict__ ln1b,
    const float* __restrict__ dW1, const float* __restrict__ db1,
    const float* __restrict__ rW1, const float* __restrict__ rb1,
    const float* __restrict__ rel, const float* __restrict__ dW2,
    const float* __restrict__ rW2, const float* __restrict__ vW,
    const float* __restrict__ vb,  const float* __restrict__ oW,
    USHORT* __restrict__ norm,
    USHORT* __restrict__ WnTg, USHORT* __restrict__ WcTg, USHORT* __restrict__ VTg,
    float* __restrict__ preg, float* __restrict__ vboWg, float* __restrict__ w2g)
{
    const int blk = blockIdx.x, t = threadIdx.x;
    if (blk >= 354) {                     // ---- LN1 ----
        const int p = (blk - 354) * 4 + (t >> 6);
        const int lane = t & 63;
        const float2 x = ((const float2*)(tok + (size_t)p * 128))[lane];
        float s = x.x + x.y;
        for (int m = 1; m < 64; m <<= 1) s += __shfl_xor(s, m);
        const float mean = s * (1.f / 128.f);
        const float d0 = x.x - mean, d1 = x.y - mean;
        float q = d0 * d0 + d1 * d1;
        for (int m = 1; m < 64; m <<= 1) q += __shfl_xor(q, m);
        const float rstd = rsqrtf(q * (1.f / 128.f) + 1e-5f);
        const float2 gg = ((const float2*)ln1g)[lane], bb = ((const float2*)ln1b)[lane];
        ((unsigned*)norm)[(size_t)p * 64 + lane] =
            (unsigned)f2bf(d0 * rstd * gg.x + bb.x) |
            ((unsigned)f2bf(d1 * rstd * gg.y + bb.y) << 16);
        return;
    }
    if (blk < 72) {                       // VTg [128][144] = perm(vW@oW)^T
        int idx = blk * 256 + t;
        int n = ((idx >> 4) * 7282) >> 16;
        int k = idx - n * 144;
        int r = k >> 4, tt = k & 15, c2 = r + 9 * tt;
        float acc = 0.f;
        if (c2 < 128)
            for (int j = 0; j < 128; ++j) acc += vW[c2 * 128 + j] * oW[j * 128 + n];
        VTg[idx] = f2bf(acc);
    } else if (blk < 216) {               // WnTg [256][144] = perm(W1b-W1c)^T
        int idx = (blk - 72) * 256 + t;
        int n = ((idx >> 4) * 7282) >> 16;
        int k = idx - n * 144;
        int r = k >> 4, tt = k & 15, c2 = r + 9 * tt;
        int col = n & 127;
        const float* W = (n < 128) ? dW1 : rW1;
        float val = 0.f;
        if (c2 < 128) val = W[(128 + c2) * 128 + col] - W[(256 + c2) * 128 + col];
        WnTg[idx] = f2bf(val);
    } else if (blk < 344) {               // WcTg [256][128] = (W1a+W1c)^T
        int idx = (blk - 216) * 256 + t;
        int n = idx >> 7, c = idx & 127, col = n & 127;
        const float* W = (n < 128) ? dW1 : rW1;
        WcTg[idx] = f2bf(W[c * 128 + col] + W[(256 + c) * 128 + col]);
    } else if (blk < 353) {               // preg[9][256] = rel@W1d + b1
        int n2 = blk - 344; int h = t;
        float acc;
        if (h < 128) {
            acc = db1[h];
            for (int r = 0; r < 8; ++r) acc += rel[n2 * 8 + r] * dW1[(384 + r) * 128 + h];
        } else {
            int hh = h - 128;
            acc = rb1[hh];
            for (int r = 0; r < 8; ++r) acc += rel[n2 * 8 + r] * rW1[(384 + r) * 128 + hh];
        }
        preg[n2 * 256 + h] = acc;
    } else {
        if (t < 128) {
            float acc = 0.f;
            for (int j = 0; j < 128; ++j) acc += vb[j] * oW[j * 128 + t];
            vboWg[t] = acc;
            w2g[t] = dW2[t];
            w2g[128 + t] = rW2[t];
        }
    }
}

// ---------------------------------------------------------------------------
// gather split (T14): issue global loads early into regs, LDS-write later.
// !ok lanes are zeroed at load time; a zero (instead of garbage) feeding the
// next lane's slot15 via shfl_down is fine — slot15 has zero weight.
// ---------------------------------------------------------------------------
__device__ __forceinline__ void gather_load(
    uint2 (&pf)[9], const USHORT* __restrict__ nb,
    int n2, int y, int bI, int tid)
{
    const int x = tid >> 2, q = tid & 3;
    #pragma unroll
    for (int r = 0; r < 9; ++r) {
        int u = 2 * n2 + r;
        int n = (u >= 18) ? (u - 18) : ((u >= 9) ? (u - 9) : u);
        int v = n2 * 128 + r;
        int c0 = (v * 7282) >> 16;                 // v/9
        int dyq = (n * 22) >> 6;                   // n/3
        int dx = n - 3 * dyq - 1;
        int dy = dyq - 1;
        int sy = y + dy, sx = x + dx;
        bool ok = ((unsigned)sy < 128u) && ((unsigned)sx < 128u);
        int e0 = (c0 & ~1) + 4 * q;
        size_t gidx = ((size_t)((bI * 128 + (ok ? sy : 0)) * 128 + (ok ? sx : 0))) * 128 + e0;
        const unsigned* gp = (const unsigned*)nb + (gidx >> 1);
        unsigned dw0 = gp[0], dw1 = gp[1];
        pf[r].x = ok ? dw0 : 0u;
        pf[r].y = ok ? dw1 : 0u;
    }
}

__device__ __forceinline__ void gather_store(
    USHORT* __restrict__ Ash, const uint2 (&pf)[9], int n2, int tid)
{
    const int x = tid >> 2, q = tid & 3;
    #pragma unroll
    for (int r = 0; r < 9; ++r) {
        int v = n2 * 128 + r;
        int c0 = (v * 7282) >> 16;
        unsigned dw0 = pf[r].x, dw1 = pf[r].y;
        unsigned nxt = (unsigned)__shfl_down((int)dw0, 1);   // feeds slot15 (zero-wt)
        unsigned o0, o1;
        if (c0 & 1) { o0 = (dw0 >> 16) | (dw1 << 16); o1 = (dw1 >> 16) | (nxt << 16); }
        else        { o0 = dw0;                       o1 = dw1; }
        *(uint2*)(Ash + x * AW + 16 * r + 4 * q) = make_uint2(o0, o1);
    }
}

// ---------------------------------------------------------------------------
// k_edge: 256 blocks (one image row each), 512 threads = 8 waves = 2M x 4N.
// MFMA 32x32x16 bf16; C/D: col=lane&31, row=(reg&3)+8*(reg>>2)+4*(lane>>5).
// LDS 158720 B: Wsh[256][152] | Ash[128][152] | VTl[128][152] | w2L | sums
// Per-n2 barriers: A (Ash reads done / sums final), B (Ash(n2+1) + gate ready)
// ---------------------------------------------------------------------------
__global__ __launch_bounds__(512, 2) void k_edge(
    const float* __restrict__ tok, const float* __restrict__ ln2g,
    const float* __restrict__ ln2b, const USHORT* __restrict__ nb,
    const USHORT* __restrict__ WnTg, const USHORT* __restrict__ WcTg,
    const USHORT* __restrict__ VTg, const float* __restrict__ preg,
    const float* __restrict__ vboWg, const float* __restrict__ w2g,
    const float* __restrict__ db2p, const float* __restrict__ rb2p,
    const float* __restrict__ gmp, const float* __restrict__ lmp,
    const float* __restrict__ bip, const float* __restrict__ obp,
    float* __restrict__ out)
{
    extern __shared__ char smem[];
    USHORT* Wsh  = (USHORT*)smem;                    // [256][152] = 77824
    USHORT* Ash  = (USHORT*)(smem + 77824);          // [128][152] = 38912
    USHORT* VTl  = (USHORT*)(smem + 116736);         // [128][152] = 38912
    float*  w2L  = (float*)(smem + 155648);          // 1024
    float*  dsum = (float*)(smem + 156672);
    float*  rsum = (float*)(smem + 157184);
    float*  gateL= (float*)(smem + 157696);
    float*  sgL  = (float*)(smem + 158208);          // end 158720
    float*  updF = (float*)smem;                     // final alias (64 KB)

    const int tid = threadIdx.x;
    const int lane = tid & 63, wave = tid >> 6, hi = lane >> 5, l31 = lane & 31;
    const int mw = wave & 1, nw = wave >> 1;
    const int blk = blockIdx.x;
    const int bI = blk >> 7;
    const int y = ((blk & 7) << 4) | ((blk >> 3) & 15);   // XCD band swizzle
    const int p0 = (bI * 128 + y) * 128;

    // ---- stage Wc + center A + VoW + w2; zero sums ----
    for (int i = tid; i < 4096; i += 512) {
        int n = i >> 4, kv = i & 15;
        *(v8u*)(Wsh + n * AW + kv * 8) = *(const v8u*)(WcTg + n * 128 + kv * 8);
    }
    for (int i = tid; i < 2048; i += 512) {
        int x = i >> 4, kv = i & 15;
        *(v8u*)(Ash + x * AW + kv * 8) = *(const v8u*)(nb + (size_t)(p0 + x) * 128 + kv * 8);
    }
    for (int i = tid; i < 2304; i += 512) {
        int n = (i * 3641) >> 16;                    // i/18
        int kv = i - n * 18;
        *(v8u*)(VTl + n * AW + kv * 8) = *(const v8u*)(VTg + n * 144 + kv * 8);
    }
    if (tid < 256) w2L[tid] = w2g[tid];
    if (tid < 128) { dsum[tid] = 0.f; rsum[tid] = 0.f; sgL[tid] = 0.f; }
    __syncthreads();

    // ---- center GEMM (K=128) ----
    v16f cp[2][2];
    #pragma unroll
    for (int a = 0; a < 2; ++a)
        for (int b = 0; b < 2; ++b)
            for (int e = 0; e < 16; ++e) cp[a][b][e] = 0.f;
    #pragma unroll
    for (int ks = 0; ks < 8; ++ks) {
        v8bf af0 = *(const v8bf*)(Ash + (mw * 64 + l31) * AW + ks * 16 + hi * 8);
        v8bf af1 = *(const v8bf*)(Ash + (mw * 64 + 32 + l31) * AW + ks * 16 + hi * 8);
        v8bf bf0 = *(const v8bf*)(Wsh + (nw * 64 + l31) * AW + ks * 16 + hi * 8);
        v8bf bf1 = *(const v8bf*)(Wsh + (nw * 64 + 32 + l31) * AW + ks * 16 + hi * 8);
        cp[0][0] = __builtin_amdgcn_mfma_f32_32x32x16_bf16(af0, bf0, cp[0][0], 0, 0, 0);
        cp[0][1] = __builtin_amdgcn_mfma_f32_32x32x16_bf16(af0, bf1, cp[0][1], 0, 0, 0);
        cp[1][0] = __builtin_amdgcn_mfma_f32_32x32x16_bf16(af1, bf0, cp[1][0], 0, 0, 0);
        cp[1][1] = __builtin_amdgcn_mfma_f32_32x32x16_bf16(af1, bf1, cp[1][1], 0, 0, 0);
    }
    __syncthreads();

    // ---- stage permuted Wn over Wc; first gather (reg round-trip) ----
    for (int i = tid; i < 4608; i += 512) {
        int n = (i * 3641) >> 16;
        int kv = i - n * 18;
        *(v8u*)(Wsh + n * AW + kv * 8) = *(const v8u*)(WnTg + n * 144 + kv * 8);
    }
    {
        uint2 pf0[9];
        gather_load(pf0, nb, 0, y, bI, tid);
        gather_store(Ash, pf0, 0, tid);
    }

    const float gmv = gmp[0], lmv = lmp[0], biv = bip[0];
    const float db2v = db2p[0], rb2v = rb2p[0];
    const float wv0 = w2L[nw * 64 + l31];
    const float wv1 = w2L[nw * 64 + 32 + l31];

    v16f acc3[2];
    #pragma unroll
    for (int a = 0; a < 2; ++a)
        for (int e = 0; e < 16; ++e) acc3[a][e] = 0.f;

    __syncthreads();                      // pre-loop: Wn + Ash(0) ready

    for (int n2 = 0; n2 < 9; ++n2) {
        const float pv0 = preg[n2 * 256 + nw * 64 + l31];
        const float pv1 = preg[n2 * 256 + nw * 64 + 32 + l31];

        // prefetch next tile's global loads NOW — latency hides under MFMA
        uint2 pf[9];
        if (n2 < 8) gather_load(pf, nb, n2 + 1, y, bI, tid);

        // ---- edge GEMM: acc = cp + A_{n2} @ Wn (K'=144) ----
        v16f acc[2][2];
        #pragma unroll
        for (int a = 0; a < 2; ++a)
            for (int b = 0; b < 2; ++b) acc[a][b] = cp[a][b];
        #pragma unroll
        for (int ks = 0; ks < 9; ++ks) {
            v8bf af0 = *(const v8bf*)(Ash + (mw * 64 + l31) * AW + ks * 16 + hi * 8);
            v8bf af1 = *(const v8bf*)(Ash + (mw * 64 + 32 + l31) * AW + ks * 16 + hi * 8);
            v8bf bf0 = *(const v8bf*)(Wsh + (nw * 64 + l31) * AW + ks * 16 + hi * 8);
            v8bf bf1 = *(const v8bf*)(Wsh + (nw * 64 + 32 + l31) * AW + ks * 16 + hi * 8);
            acc[0][0] = __builtin_amdgcn_mfma_f32_32x32x16_bf16(af0, bf0, acc[0][0], 0, 0, 0);
            acc[0][1] = __builtin_amdgcn_mfma_f32_32x32x16_bf16(af0, bf1, acc[0][1], 0, 0, 0);
            acc[1][0] = __builtin_amdgcn_mfma_f32_32x32x16_bf16(af1, bf0, acc[1][0], 0, 0, 0);
            acc[1][1] = __builtin_amdgcn_mfma_f32_32x32x16_bf16(af1, bf1, acc[1][1], 0, 0, 0);
        }
        // ---- epilogue: gelu(h)·w2, DPP half-wave reduce, atomic per row ----
        #pragma unroll
        for (int mt = 0; mt < 2; ++mt) {
            float part[16];
            #pragma unroll
            for (int rr = 0; rr < 16; ++rr) {
                float h0 = acc[mt][0][rr] + pv0;
                float h1 = acc[mt][1][rr] + pv1;
                float s0 = __builtin_amdgcn_rcpf(1.f + __expf(-1.702f * h0));
                float s1 = __builtin_amdgcn_rcpf(1.f + __expf(-1.702f * h1));
                part[rr] = h0 * s0 * wv0 + h1 * s1 * wv1;
            }
            #pragma unroll
            for (int rr = 0; rr < 16; ++rr) part[rr] = red32half(part[rr]);
            if (l31 == 31) {              // lanes 31 (hi=0) and 63 (hi=1)
                float* tgt = (nw < 2) ? dsum : rsum;
                #pragma unroll
                for (int rr = 0; rr < 16; ++rr) {
                    int row = mw * 64 + mt * 32 + (rr & 3) + 8 * (rr >> 2) + 4 * hi;
                    atomicAdd(&tgt[row], part[rr]);
                }
            }
        }
        // ---- message GEMM: P = A_{n2} @ VoW (N=128, per-wave 32-col slice) ----
        v16f P[2];
        #pragma unroll
        for (int a = 0; a < 2; ++a)
            for (int e = 0; e < 16; ++e) P[a][e] = 0.f;
        #pragma unroll
        for (int ks = 0; ks < 9; ++ks) {
            v8bf af0 = *(const v8bf*)(Ash + (mw * 64 + l31) * AW + ks * 16 + hi * 8);
            v8bf af1 = *(const v8bf*)(Ash + (mw * 64 + 32 + l31) * AW + ks * 16 + hi * 8);
            v8bf vf  = *(const v8bf*)(VTl + (nw * 32 + l31) * AW + ks * 16 + hi * 8);
            P[0] = __builtin_amdgcn_mfma_f32_32x32x16_bf16(af0, vf, P[0], 0, 0, 0);
            P[1] = __builtin_amdgcn_mfma_f32_32x32x16_bf16(af1, vf, P[1], 0, 0, 0);
        }
        __syncthreads();                  // A: sums final, Ash reads complete
        if (n2 < 8) gather_store(Ash, pf, n2 + 1, tid);   // regs -> LDS
        if (tid < 128) {
            float d = dsum[tid] + db2v, rr = rsum[tid] + rb2v;
            float sp = fmaxf(rr, 0.f) + log1pf(__expf(-fabsf(rr)));
            float e = gmv * d / (lmv * sp + 1e-6f) + biv;
            e = fminf(fmaxf(e, -3.f), 3.f);
            float gt = 1.f / (1.f + __expf(-e));
            gateL[tid] = gt; sgL[tid] += gt;
            dsum[tid] = 0.f; rsum[tid] = 0.f;
        }
        __syncthreads();                  // B: gate + Ash(n2+1) ready
        // ---- acc3 += g ⊙ P (broadcast float4 gate reads) ----
        #pragma unroll
        for (int mt = 0; mt < 2; ++mt) {
            const float4* gq = (const float4*)&gateL[mw * 64 + mt * 32 + 4 * hi];
            float4 ga = gq[0], gb = gq[2], gc = gq[4], gd = gq[6];
            float gs[16] = {ga.x, ga.y, ga.z, ga.w, gb.x, gb.y, gb.z, gb.w,
                            gc.x, gc.y, gc.z, gc.w, gd.x, gd.y, gd.z, gd.w};
            #pragma unroll
            for (int rr = 0; rr < 16; ++rr) acc3[mt][rr] += gs[rr] * P[mt][rr];
        }
    }

    // ---- final: mass, update, LN2 ----
    if (tid < 128) {
        float s = sgL[tid];
        float m = fmaxf(s, 1e-6f);
        dsum[tid] = 1.f / m;     // 1/mass
        rsum[tid] = s / m;       // sg/mass
    }
    __syncthreads();

    {
        const int colc = nw * 32 + l31;
        const float vbw = vboWg[colc], obv = obp[colc];
        #pragma unroll
        for (int mt = 0; mt < 2; ++mt) {
            const int base = mw * 64 + mt * 32 + 4 * hi;
            const float4* iq = (const float4*)&dsum[base];
            const float4* sq = (const float4*)&rsum[base];
            float4 ia = iq[0], ib = iq[2], ic = iq[4], id = iq[6];
            float4 sa = sq[0], sb = sq[2], sc = sq[4], sd = sq[6];
            float iv[16] = {ia.x, ia.y, ia.z, ia.w, ib.x, ib.y, ib.z, ib.w,
                            ic.x, ic.y, ic.z, ic.w, id.x, id.y, id.z, id.w};
            float sv[16] = {sa.x, sa.y, sa.z, sa.w, sb.x, sb.y, sb.z, sb.w,
                            sc.x, sc.y, sc.z, sc.w, sd.x, sd.y, sd.z, sd.w};
            #pragma unroll
            for (int rr = 0; rr < 16; ++rr) {
                int row = base + (rr & 3) + 8 * (rr >> 2);
                updF[row * 128 + colc] = acc3[mt][rr] * iv[rr] + vbw * sv[rr] + obv;
            }
        }
    }
    __syncthreads();

    const float g20 = ln2g[lane], g21 = ln2g[lane + 64];
    const float b20 = ln2b[lane], b21 = ln2b[lane + 64];
    for (int q2 = 0; q2 < 16; ++q2) {
        int p = wave * 16 + q2;
        size_t gp = (size_t)(p0 + p) * 128;
        float x0 = tok[gp + lane]      + updF[p * 128 + lane];
        float x1 = tok[gp + lane + 64] + updF[p * 128 + lane + 64];
        float mean = bcast63(red64(x0 + x1)) * (1.f / 128.f);
        float d0 = x0 - mean, d1 = x1 - mean;
        float rstd = rsqrtf(bcast63(red64(d0 * d0 + d1 * d1)) * (1.f / 128.f) + 1e-5f);
        out[gp + lane]      = d0 * rstd * g20 + b20;
        out[gp + lane + 64] = d1 * rstd * g21 + b21;
    }
}

// ---------------------------------------------------------------------------
extern "C" void kernel_launch(void* const* d_in, const int* in_sizes, int n_in,
                              void* d_out, int out_size, void* d_ws, size_t ws_size,
                              hipStream_t stream) {
    const float* tok  = (const float*)d_in[0];
    const float* ln1g = (const float*)d_in[1];
    const float* ln1b = (const float*)d_in[2];
    const float* ln2g = (const float*)d_in[3];
    const float* ln2b = (const float*)d_in[4];
    const float* rel  = (const float*)d_in[5];
    const float* dW1  = (const float*)d_in[6];
    const float* db1  = (const float*)d_in[7];
    const float* dW2  = (const float*)d_in[8];
    const float* db2  = (const float*)d_in[9];
    const float* rW1  = (const float*)d_in[10];
    const float* rb1  = (const float*)d_in[11];
    const float* rW2  = (const float*)d_in[12];
    const float* rb2  = (const float*)d_in[13];
    const float* vW   = (const float*)d_in[14];
    const float* vb   = (const float*)d_in[15];
    const float* oW   = (const float*)d_in[16];
    const float* ob   = (const float*)d_in[17];
    const float* gm   = (const float*)d_in[18];
    const float* lm   = (const float*)d_in[19];
    const float* bi   = (const float*)d_in[20];
    float* out = (float*)d_out;

    char* w = (char*)d_ws;
    USHORT* norm = (USHORT*)w; w += 8388608;   // [32768][128] bf16 (gather may
                                               //  over-read 2 elems into WnTg: finite)
    USHORT* WnTg = (USHORT*)w; w += 73728;     // [256][144] bf16, permuted+zero-pad
    USHORT* WcTg = (USHORT*)w; w += 65536;     // [256][128] bf16
    USHORT* VTg  = (USHORT*)w; w += 36864;     // [128][144] bf16, permuted+zero-pad
    float*  preg = (float*)w;  w += 9216;      // [9][256] f32
    float*  vboWg= (float*)w;  w += 512;       // [128] f32
    float*  w2g  = (float*)w;  w += 1024;      // [256] f32

    hipFuncSetAttribute((const void*)k_edge,
                        hipFuncAttributeMaxDynamicSharedMemorySize, 158720);

    hipLaunchKernelGGL(k_setup, dim3(8546), dim3(256), 0, stream,
                       tok, ln1g, ln1b, dW1, db1, rW1, rb1, rel, dW2, rW2,
                       vW, vb, oW, norm, WnTg, WcTg, VTg, preg, vboWg, w2g);
    hipLaunchKernelGGL(k_edge, dim3(256), dim3(512), 158720, stream,
                       tok, ln2g, ln2b, norm, WnTg, WcTg, VTg, preg, vboWg, w2g,
                       db2, rb2, gm, lm, bi, ob, out);
}